// Round 8
// baseline (93.235 us; speedup 1.0000x reference)
//
#include <hip/hip_runtime.h>
#include <hip/hip_bf16.h>

// out = softmax((X Wq + bq)(X Wk + bk)^T / 8) (X Wv + bv) Wo + bo
// All prune/straight-through ops in the reference are value-wise identity.
//
// Pipeline (all bf16 MFMA 16x16x32, fp32 accum):
//   k_prep: fused {hs->bf16 A [4736][768] w/ zero pad | W^T bf16 x4 | kh/vt pad zero}
//   k_gemm: fused QKV GEMM (N=2304), 128x128 tile, 256 threads (4 waves,
//           64x64/wave -> 512B LDS-read per MFMA, balanced), double-buffered
//           gload_lds with counted vmcnt(8), XCD-chunked swizzle; epilogue
//           stages tile in LDS (V transposed) -> 16B coalesced stores.
//           mode 3 = ctx@Wo+bo -> d_out fp32
//   k_attn: flash attention, swapped-operand form: S^T = mfma(K,Q) so softmax
//           stats are lane-local (2 shuffles), P^T packed b64 writes + b128
//           reads, O^T = mfma(V^T, P^T). K/V double-buffered gload_lds.

#define B_ 8
#define S_ 577
#define H_ 768
#define NH_ 12
#define HD_ 64
#define M_ (B_*S_)     /* 4616 */
#define MPAD 4736      /* 37*128 */
#define BH_ (B_*NH_)   /* 96 */
#define SKPAD 640      /* padded key count */
#define LTS 136        /* padded LDS row stride (shorts) for epilogue tile */

typedef __attribute__((ext_vector_type(8))) short short8;
typedef __attribute__((ext_vector_type(4))) short s16x4;
typedef __attribute__((ext_vector_type(4))) float f32x4;

__device__ inline unsigned short f2bf(float f){
    unsigned int u = __float_as_uint(f);
    u = u + 0x7fffu + ((u>>16)&1u);     // round-to-nearest-even
    return (unsigned short)(u>>16);
}

__device__ inline void gload_lds16(const short* g, short* l){
    __builtin_amdgcn_global_load_lds((const __attribute__((address_space(1))) void*)g,
                                     (__attribute__((address_space(3))) void*)l, 16, 0, 0);
}

// fused prep: blocks [0,1776) cvt | [1776,2352) wt | [2352,2733) pad
__global__ __launch_bounds__(256) void k_prep(
    const float* __restrict__ hs, short* __restrict__ abf,
    const float* __restrict__ Wq, const float* __restrict__ Wk,
    const float* __restrict__ Wv, const float* __restrict__ Wo,
    short* __restrict__ Tq, short* __restrict__ Tk,
    short* __restrict__ Tv, short* __restrict__ To,
    short* __restrict__ kh, short* __restrict__ vt)
{
    const int bid = blockIdx.x, t = threadIdx.x;
    if(bid < 1776){
        int i = bid*256 + t;
        if(bid >= 1731){ *(short8*)(abf + (size_t)i*8) = (short8){}; return; }
        const float4* p = (const float4*)(hs + (size_t)i*8);
        float4 a = p[0], b = p[1];
        short8 v;
        v[0]=(short)f2bf(a.x); v[1]=(short)f2bf(a.y); v[2]=(short)f2bf(a.z); v[3]=(short)f2bf(a.w);
        v[4]=(short)f2bf(b.x); v[5]=(short)f2bf(b.y); v[6]=(short)f2bf(b.z); v[7]=(short)f2bf(b.w);
        *(short8*)(abf + (size_t)i*8) = v;
    } else if(bid < 2352){
        int zidx = bid - 1776;
        int z = zidx & 3, rem = zidx >> 2;
        int kx = rem % 12, ny = rem / 12;
        const float* W = z==0?Wq: z==1?Wk: z==2?Wv:Wo;
        short*       T = z==0?Tq: z==1?Tk: z==2?Tv:To;
        __shared__ float lds[64][65];
        int k0 = kx*64, n0 = ny*64;
        for(int i=0;i<4;i++){
            int row = i*16 + (t>>4);
            int col = (t&15)*4;
            float4 v = *(const float4*)&W[(k0+row)*768 + n0 + col];
            lds[row][col]=v.x; lds[row][col+1]=v.y; lds[row][col+2]=v.z; lds[row][col+3]=v.w;
        }
        __syncthreads();
        for(int i=0;i<4;i++){
            int n = i*16 + (t>>4);
            int k4 = (t&15)*4;
            for(int j=0;j<4;j++)
                T[(n0+n)*768 + k0 + k4 + j] = (short)f2bf(lds[k4+j][n]);
        }
    } else {
        int tid = (bid-2352)*256 + t;
        short8 z = {};
        if(tid < 48384){
            int row_id = tid>>3, ch = tid&7;
            int bh = row_id/63, r = row_id - bh*63;
            *(short8*)&kh[((size_t)bh*SKPAD + 577 + r)*64 + ch*8] = z;
        } else if(tid < 97536){
            int j = tid - 48384;
            int row_id = j>>3, ch = j&7;
            int bh = row_id>>6, d = row_id&63;
            *(short8*)&vt[((size_t)bh*64 + d)*SKPAD + 576 + ch*8] = z;
        }
    }
}

// 128x128 tile GEMM, 4 waves (64x64/wave), double-buffered counted-vmcnt K-loop,
// XCD-chunked swizzle. mode 0: QKV fused; mode 3: ctx@Wo+bo -> fp32
__global__ __launch_bounds__(256) void k_gemm(
    const short* __restrict__ A, const short* __restrict__ T,
    const float* __restrict__ b0, const float* __restrict__ b1, const float* __restrict__ b2,
    short* __restrict__ oq, short* __restrict__ ok, short* __restrict__ ovt,
    float* __restrict__ of, int mode, int NT)
{
    __shared__ short sh[32768];            // 64KB: dbuf K-loop; epilogue reuses [0,34816B)
    const int t = threadIdx.x;

    const int nwg = gridDim.x;
    const int q8 = nwg>>3, r8 = nwg&7;
    const int xcd = blockIdx.x&7, cidx = blockIdx.x>>3;
    const int wg = (xcd<r8 ? xcd*(q8+1) : r8*(q8+1) + (xcd-r8)*q8) + cidx;
    const int mt = wg/NT, ntile = wg - mt*NT;
    const int m0 = mt*128, n0 = ntile*128;

    const int seg = (mode==3)? 0 : n0/768;
    const float* bias = (mode==3)? b0 : (seg==0?b0: seg==1?b1:b2);
    const int nlb = (mode==3)? n0 : n0 - seg*768;

    const int w = t>>6, lane = t&63, g = lane>>4, c = lane&15;
    const int wm = w>>1, wn = w&1;

    // staging: lane l -> row (l>>3), dest 16B-slot (l&7); source chunk (l&7)^(row&7)
    const int lrow = lane>>3;
    const int lcol = ((lane&7) ^ lrow) * 8;
    const short* pa = A + (size_t)(m0 + w*32 + lrow)*768 + lcol;
    const short* pb = T + (size_t)(n0 + w*32 + lrow)*768 + lcol;

    f32x4 acc[4][4] = {};

    // prologue: stage K-step 0 into buffer 0 (8 loads/thread)
    #pragma unroll
    for(int i=0;i<4;i++){
        gload_lds16(pa + (size_t)i*8*768, &sh[(w*32+i*8)*64]);
        gload_lds16(pb + (size_t)i*8*768, &sh[8192 + (w*32+i*8)*64]);
    }
    int bb = 0;
    for(int kk=0; kk<12; kk++){
        if(kk<11){
            short* dstA = &sh[(bb^1)*16384];
            short* dstB = dstA + 8192;
            #pragma unroll
            for(int i=0;i<4;i++){
                gload_lds16(pa + (size_t)i*8*768 + (kk+1)*64, &dstA[(w*32+i*8)*64]);
                gload_lds16(pb + (size_t)i*8*768 + (kk+1)*64, &dstB[(w*32+i*8)*64]);
            }
            asm volatile("s_waitcnt vmcnt(8)" ::: "memory");
        } else {
            asm volatile("s_waitcnt vmcnt(0)" ::: "memory");
        }
        __builtin_amdgcn_s_barrier();
        asm volatile("" ::: "memory");

        const short* LA = &sh[bb*16384];
        const short* LB = LA + 8192;
        short8 af[4][2], bfv[4][2];
        #pragma unroll
        for(int mi=0; mi<4; mi++){
            int row = wm*64 + mi*16 + c;
            int rx = (row&7)<<3;
            af[mi][0] = *(const short8*)&LA[row*64 + ((g*8) ^ rx)];
            af[mi][1] = *(const short8*)&LA[row*64 + ((32 + g*8) ^ rx)];
        }
        #pragma unroll
        for(int ni=0; ni<4; ni++){
            int row = wn*64 + ni*16 + c;
            int rx = (row&7)<<3;
            bfv[ni][0] = *(const short8*)&LB[row*64 + ((g*8) ^ rx)];
            bfv[ni][1] = *(const short8*)&LB[row*64 + ((32 + g*8) ^ rx)];
        }
        #pragma unroll
        for(int mi=0; mi<4; mi++)
            #pragma unroll
            for(int ni=0; ni<4; ni++){
                acc[mi][ni] = __builtin_amdgcn_mfma_f32_16x16x32_bf16(af[mi][0], bfv[ni][0], acc[mi][ni], 0,0,0);
                acc[mi][ni] = __builtin_amdgcn_mfma_f32_16x16x32_bf16(af[mi][1], bfv[ni][1], acc[mi][ni], 0,0,0);
            }
        asm volatile("s_waitcnt lgkmcnt(0)" ::: "memory");
        __builtin_amdgcn_s_barrier();
        asm volatile("" ::: "memory");
        bb ^= 1;
    }

    if(mode==3){
        #pragma unroll
        for(int mi=0; mi<4; mi++) for(int ni=0; ni<4; ni++){
            #pragma unroll
            for(int r=0; r<4; r++){
                int m = m0 + wm*64 + mi*16 + g*4 + r;   // C/D: row=(lane>>4)*4+reg
                int n = n0 + wn*64 + ni*16 + c;         // C/D: col=lane&15
                if(m >= M_) continue;
                of[(size_t)m*768 + n] = acc[mi][ni][r] + bias[n];
            }
        }
        return;
    }

    // mode 0 epilogue: stage bf16 tile to LDS (V-segment transposed), then
    // 16B-coalesced stores.
    if(seg==2){
        #pragma unroll
        for(int mi=0;mi<4;mi++)
            #pragma unroll
            for(int ni=0;ni<4;ni++){
                int nl_ = wn*64 + ni*16 + c;
                float bv = bias[nlb + nl_];
                s16x4 pk;
                #pragma unroll
                for(int r=0;r<4;r++) pk[r] = (short)f2bf(acc[mi][ni][r] + bv);
                int ml0 = wm*64 + mi*16 + g*4;
                *(s16x4*)&sh[nl_*LTS + ml0] = pk;       // transposed: [n][m]
            }
    } else {
        #pragma unroll
        for(int mi=0;mi<4;mi++)
            #pragma unroll
            for(int ni=0;ni<4;ni++){
                int nl_ = wn*64 + ni*16 + c;
                float bv = bias[nlb + nl_];
                #pragma unroll
                for(int r=0;r<4;r++){
                    int ml = wm*64 + mi*16 + g*4 + r;
                    sh[ml*LTS + nl_] = (short)f2bf(acc[mi][ni][r] + bv);
                }
            }
    }
    __syncthreads();

    #pragma unroll
    for(int i=0;i<8;i++){
        int idx = i*256 + t;
        int rp = idx>>4, ch = idx&15;
        short8 v8 = *(const short8*)&sh[rp*LTS + ch*8];
        if(seg==2){
            int nl = nlb + rp, hh = nl>>6, dd = nl&63;
            int mg = m0 + ch*8;
            if(mg < M_){
                int b0_ = mg/S_, s0 = mg - b0_*S_;
                if(s0+7 < S_ && mg+7 < M_){
                    *(short8*)&ovt[(((size_t)b0_*NH_+hh)*HD_+dd)*SKPAD + s0] = v8;
                } else {
                    for(int j=0;j<8;j++){
                        int m=mg+j;
                        if(m<M_){ int bj=m/S_, sj=m-bj*S_;
                            ovt[(((size_t)bj*NH_+hh)*HD_+dd)*SKPAD+sj]=v8[j]; }
                    }
                }
            }
        } else {
            int m = m0 + rp;
            if(m < M_){
                int b0_ = m/S_, s0 = m - b0_*S_;
                int nl = nlb + ch*8, hh = nl>>6, dd = nl&63;
                if(seg==1) *(short8*)&ok[(((size_t)b0_*NH_+hh)*SKPAD + s0)*HD_ + dd] = v8;
                else       *(short8*)&oq[(((size_t)b0_*NH_+hh)*S_   + s0)*HD_ + dd] = v8;
            }
        }
    }
}

// flash attention, swapped-operand form. QBLK=128 (2 q-frags/wave).
// S^T = mfma(K_frag, Q_frag): lane holds S^T[key=16nt+4g+r][q=c] -> softmax
// stats lane-local per q (2 shfl_xor over g). P^T staged as packed b64 with
// slot-XOR swizzle, read back as b128 B-frags. O^T = mfma(V^T_frag, P^T_frag).
__global__ __launch_bounds__(256) void k_attn(
    const short* __restrict__ qh, const short* __restrict__ kh, const short* __restrict__ vt,
    short* __restrict__ ctx)
{
    __shared__ short lK[2][64*64], lV[2][64*64], lP[4*2048];
    const int t = threadIdx.x;
    const int w = t>>6, lane = t&63, g = lane>>4, c = lane&15;
    const int bh = blockIdx.x, b = bh/NH_, h = bh%NH_;
    const int q0 = blockIdx.y*128;

    // per-wave Q staging (32 rows) into own lP region (guarded), then frags to regs
    #pragma unroll
    for(int i=0;i<4;i++){
        int row = i*8 + (lane>>3);
        int e8 = (lane&7)*8;
        int s = q0 + w*32 + row;
        short8 v = {};
        if(s < S_) v = *(const short8*)&qh[((size_t)bh*S_ + s)*HD_ + e8];
        *(short8*)&lP[w*2048 + row*64 + (e8 ^ ((row&7)<<3))] = v;
    }
    short8 qf[2][2];
    #pragma unroll
    for(int qi=0; qi<2; qi++)
        #pragma unroll
        for(int ks=0; ks<2; ks++)
            qf[qi][ks] = *(const short8*)&lP[w*2048 + (qi*16+c)*64 + ((ks*32+g*8) ^ ((c&7)<<3))];

    const int srow = lane>>3;
    const int sw8 = ((lane&7) ^ srow)*8;
    const short* pk0 = kh + ((size_t)bh*SKPAD + w*16 + srow)*64 + sw8;
    const short* pv0 = vt + ((size_t)bh*64 + w*16 + srow)*SKPAD + sw8;

    #pragma unroll
    for(int i=0;i<2;i++){
        gload_lds16(pk0 + i*8*64,    &lK[0][(w*16+i*8)*64]);
        gload_lds16(pv0 + i*8*SKPAD, &lV[0][(w*16+i*8)*64]);
    }

    float m_run[2], l_run[2];
    f32x4 O[2][4] = {};
    #pragma unroll
    for(int qi=0;qi<2;qi++){ m_run[qi] = -3e38f; l_run[qi] = 0.f; }

    int bb = 0;
    for(int kt=0; kt<10; kt++){
        if(kt<9){
            const short* pk = pk0 + (kt+1)*4096;
            const short* pv = pv0 + (kt+1)*64;
            #pragma unroll
            for(int i=0;i<2;i++){
                gload_lds16(pk + i*8*64,    &lK[bb^1][(w*16+i*8)*64]);
                gload_lds16(pv + i*8*SKPAD, &lV[bb^1][(w*16+i*8)*64]);
            }
            asm volatile("s_waitcnt vmcnt(4)" ::: "memory");
        } else {
            asm volatile("s_waitcnt vmcnt(0)" ::: "memory");
        }
        __builtin_amdgcn_s_barrier();
        asm volatile("" ::: "memory");

        const short* LK = lK[bb]; const short* LV = lV[bb];

        // S^T = K . Q^T  (lane: S^T[key=16nt+4g+r][q=c]), log2-domain scale
        float sv[2][4][4];
        #pragma unroll
        for(int nt=0; nt<4; nt++){
            int row = nt*16 + c;
            int rx = (row&7)<<3;
            short8 kf[2];
            kf[0] = *(const short8*)&LK[row*64 + ((g*8) ^ rx)];
            kf[1] = *(const short8*)&LK[row*64 + ((32+g*8) ^ rx)];
            __builtin_amdgcn_s_setprio(1);
            #pragma unroll
            for(int qi=0; qi<2; qi++){
                f32x4 sa = {};
                sa = __builtin_amdgcn_mfma_f32_16x16x32_bf16(kf[0], qf[qi][0], sa, 0,0,0);
                sa = __builtin_amdgcn_mfma_f32_16x16x32_bf16(kf[1], qf[qi][1], sa, 0,0,0);
                #pragma unroll
                for(int r=0;r<4;r++) sv[qi][nt][r] = sa[r]*0.18033688011f;  // /8 * log2(e)
            }
            __builtin_amdgcn_s_setprio(0);
        }
        if(kt==9){
            #pragma unroll
            for(int nt=0; nt<4; nt++)
                #pragma unroll
                for(int r=0;r<4;r++){
                    if(nt*16 + g*4 + r >= 1){   // key 576+off valid only at off==0
                        sv[0][nt][r] = -3e38f;
                        sv[1][nt][r] = -3e38f;
                    }
                }
        }
        // softmax: lane-local max/sum over 16 + 2 shfl over g; P^T packed b64
        #pragma unroll
        for(int qi=0; qi<2; qi++){
            float mx = sv[qi][0][0];
            #pragma unroll
            for(int nt=0; nt<4; nt++)
                #pragma unroll
                for(int r=0;r<4;r++) mx = fmaxf(mx, sv[qi][nt][r]);
            mx = fmaxf(mx, __shfl_xor(mx, 16));
            mx = fmaxf(mx, __shfl_xor(mx, 32));
            float nm = fmaxf(m_run[qi], mx);
            float fac = __builtin_amdgcn_exp2f(m_run[qi] - nm);
            m_run[qi] = nm;
            float ts = 0.f;
            #pragma unroll
            for(int nt=0; nt<4; nt++){
                s16x4 pk;
                #pragma unroll
                for(int r=0;r<4;r++){
                    float p = __builtin_amdgcn_exp2f(sv[qi][nt][r] - nm);
                    ts += p;
                    pk[r] = (short)f2bf(p);
                }
                int slot = 2*nt + (g>>1);
                *(s16x4*)&lP[w*2048 + qi*1024 + c*64 + ((slot ^ (c&7))<<3) + ((g&1)<<2)] = pk;
            }
            ts += __shfl_xor(ts, 16);
            ts += __shfl_xor(ts, 32);
            l_run[qi] = l_run[qi]*fac + ts;
            #pragma unroll
            for(int nt=0;nt<4;nt++)
                #pragma unroll
                for(int r=0;r<4;r++) O[qi][nt][r] *= fac;
        }
        // P^T fragments (B-operand): keys 32ks+8g.. at slot 4ks+g
        short8 pf[2][2];
        #pragma unroll
        for(int qi=0; qi<2; qi++)
            #pragma unroll
            for(int ks=0; ks<2; ks++)
                pf[qi][ks] = *(const short8*)&lP[w*2048 + qi*1024 + c*64 + (((4*ks+g) ^ (c&7))<<3)];

        // O^T += V^T . P^T
        __builtin_amdgcn_s_setprio(1);
        #pragma unroll
        for(int nt=0; nt<4; nt++){
            int vrow = nt*16 + c;
            int rx = (vrow&7)<<3;
            short8 vf[2];
            vf[0] = *(const short8*)&LV[vrow*64 + ((g*8) ^ rx)];
            vf[1] = *(const short8*)&LV[vrow*64 + ((32+g*8) ^ rx)];
            #pragma unroll
            for(int qi=0; qi<2; qi++){
                O[qi][nt] = __builtin_amdgcn_mfma_f32_16x16x32_bf16(vf[0], pf[qi][0], O[qi][nt], 0,0,0);
                O[qi][nt] = __builtin_amdgcn_mfma_f32_16x16x32_bf16(vf[1], pf[qi][1], O[qi][nt], 0,0,0);
            }
        }
        __builtin_amdgcn_s_setprio(0);
        asm volatile("s_waitcnt lgkmcnt(0)" ::: "memory");
        __builtin_amdgcn_s_barrier();
        asm volatile("" ::: "memory");
        bb ^= 1;
    }

    // O^T lane layout: O[qi][nt][r] = ctx[s = q0+w*32+qi*16+c][d = nt*16+4g+r]
    // -> 4 d-contiguous values per (qi,nt): 8B packed stores
    #pragma unroll
    for(int qi=0; qi<2; qi++){
        float rinv = 1.0f / l_run[qi];
        int s = q0 + w*32 + qi*16 + c;
        if(s < S_){
            #pragma unroll
            for(int nt=0; nt<4; nt++){
                s16x4 ov;
                #pragma unroll
                for(int r=0;r<4;r++) ov[r] = (short)f2bf(O[qi][nt][r] * rinv);
                *(s16x4*)&ctx[((size_t)b*S_ + s)*H_ + h*HD_ + nt*16 + g*4] = ov;
            }
        }
    }
}

extern "C" void kernel_launch(void* const* d_in, const int* in_sizes, int n_in,
                              void* d_out, int out_size, void* d_ws, size_t ws_size,
                              hipStream_t stream)
{
    const float* hs = (const float*)d_in[0];
    const float* Wq = (const float*)d_in[1];
    const float* bq = (const float*)d_in[2];
    const float* Wk = (const float*)d_in[3];
    const float* bk = (const float*)d_in[4];
    const float* Wv = (const float*)d_in[5];
    const float* bv = (const float*)d_in[6];
    const float* Wo = (const float*)d_in[7];
    const float* bo = (const float*)d_in[8];
    float* out = (float*)d_out;

    char* ws = (char*)d_ws;
    short* abf = (short*)(ws);
    short* ctx = abf;                               // reuse after QKV GEMM
    short* wqt = (short*)(ws + 7274496);
    short* wkt = (short*)(ws + 7274496 + 1179648);
    short* wvt = (short*)(ws + 7274496 + 2*1179648);
    short* wot = (short*)(ws + 7274496 + 3*1179648);
    short* qh  = (short*)(ws + 11993088);
    short* kh  = (short*)(ws + 19083264);
    short* vt  = (short*)(ws + 26947584);
    // total: 34,811,904 B

    k_prep<<<2733, 256, 0, stream>>>(hs, abf, Wq,Wk,Wv,Wo, wqt,wkt,wvt,wot, kh, vt);
    k_gemm<<<666, 256, 0, stream>>>(abf, wqt, bq,bk,bv, qh,kh,vt, nullptr, 0, 18);
    k_attn<<<dim3(96,5), 256, 0, stream>>>(qh, kh, vt, ctx);
    k_gemm<<<222, 256, 0, stream>>>(ctx, wot, bo,bo,bo, nullptr,nullptr,nullptr, out, 3, 6);
}